// Round 3
// baseline (295.350 us; speedup 1.0000x reference)
//
#include <hip/hip_runtime.h>
#include <hip/hip_bf16.h>

typedef unsigned short u16;
typedef short short8 __attribute__((ext_vector_type(8)));
typedef float floatx4 __attribute__((ext_vector_type(4)));

#define MFMA16(a, b, c) __builtin_amdgcn_mfma_f32_16x16x32_bf16((a), (b), (c), 0, 0, 0)

union U128u { uint4 q; u16 s[8]; };

__device__ __forceinline__ u16 f2bf(float f) {
  union { float f; unsigned u; } v; v.f = f;
  unsigned r = v.u + 0x7fffu + ((v.u >> 16) & 1u);
  return (u16)(r >> 16);
}

__device__ __forceinline__ float bf2f(u16 s) {
  union { unsigned u; float f; } v; v.u = ((unsigned)s) << 16;
  return v.f;
}

// pack two f32 -> bf16x2 (round-half-up) with one v_perm (attn P only)
__device__ __forceinline__ unsigned pk2(float hi, float lo) {
  union { float f; unsigned u; } a, b;
  a.f = hi; b.f = lo;
  return __builtin_amdgcn_perm(a.u + 0x8000u, b.u + 0x8000u, 0x07060302u);
}

__device__ __forceinline__ float fexp2(float x) {
#if __has_builtin(__builtin_amdgcn_exp2f)
  return __builtin_amdgcn_exp2f(x);
#else
  return exp2f(x);
#endif
}

// async global->LDS, 16B per lane. lds pointer must be wave-uniform.
__device__ __forceinline__ void async16(const u16* g, u16* l) {
  __builtin_amdgcn_global_load_lds(
      (const __attribute__((address_space(1))) unsigned int*)g,
      (__attribute__((address_space(3))) unsigned int*)l, 16, 0, 0);
}

// ---------------- merged prep: cast x, cast Wo, repack Wqkv + biases ----------------

__global__ __launch_bounds__(256) void prep_all(
    const float* __restrict__ x, const float* __restrict__ Wo,
    const float* __restrict__ Wq, const float* __restrict__ bq,
    const float* __restrict__ Wk, const float* __restrict__ bk,
    const float* __restrict__ Wv, const float* __restrict__ bv,
    u16* __restrict__ Xb, u16* __restrict__ Wob,
    u16* __restrict__ Wt, float* __restrict__ ball) {
  int bid = blockIdx.x;
  int tid = threadIdx.x;
  if (bid < 5120) {
    // cast: blocks [0,4096) -> x (1048576 float4), [4096,5120) -> Wo (262144 float4)
    const float* src = bid < 4096 ? x : Wo;
    u16* dst = bid < 4096 ? Xb : Wob;
    int i = (bid < 4096 ? bid : bid - 4096) * 256 + tid;
    float4 v = ((const float4*)src)[i];
    union { unsigned long long ll; u16 s[4]; } o;
    o.s[0] = f2bf(v.x); o.s[1] = f2bf(v.y); o.s[2] = f2bf(v.z); o.s[3] = f2bf(v.w);
    ((unsigned long long*)dst)[i] = o.ll;
    return;
  }
  int id = (bid - 5120) * 256 + tid;  // 786432 total
  int kk4 = id & 15;
  int d = (id >> 4) & 1023;
  int h = (id >> 14) & 15;
  int wsel = id >> 18;
  const float* W = wsel == 0 ? Wq : (wsel == 1 ? Wk : Wv);
  float4 v = *(const float4*)(W + ((size_t)(h * 1024 + d)) * 64 + kk4 * 4);
  int nb = wsel * 1024 + h * 64 + kk4 * 4;
  Wt[(size_t)(nb + 0) * 1024 + d] = f2bf(v.x);
  Wt[(size_t)(nb + 1) * 1024 + d] = f2bf(v.y);
  Wt[(size_t)(nb + 2) * 1024 + d] = f2bf(v.z);
  Wt[(size_t)(nb + 3) * 1024 + d] = f2bf(v.w);
  if (id < 3072) {
    int ws2 = id >> 10, hk = id & 1023;
    const float* bsrc = ws2 == 0 ? bq : (ws2 == 1 ? bk : bv);
    ball[id] = bsrc[hk];
  }
}

// ---------------- GEMM: C[M,N] = A[M,K] * B^T (B stored [N,K]) + bias, opt scale --------------

__device__ __forceinline__ void store_out(u16* p, float v) { *p = f2bf(v); }
__device__ __forceinline__ void store_out(float* p, float v) { *p = v; }

template <int BN, bool SPLITV, bool TRANS, typename OutT>
__global__ __launch_bounds__(256, 4) void gemm_bt(
    const u16* __restrict__ A, const u16* __restrict__ B,
    const float* __restrict__ bias, OutT* __restrict__ C,
    u16* __restrict__ Vtc,
    int M, int N, int K, int scaleNend, float scaleVal) {
  constexpr int TN = BN / 32;  // n-tiles per wave
  __shared__ __attribute__((aligned(16))) u16 As[128 * 64];
  __shared__ __attribute__((aligned(16))) u16 Bs[BN * 64];
  const int tid = threadIdx.x;
  const int w = tid >> 6, lane = tid & 63;
  const int l15 = lane & 15, l4 = lane >> 4;
  const int lin = blockIdx.x;
  const int xcd = lin & 7, sblk = lin >> 3;
  const int bm = xcd * 4 + (sblk & 3);   // M=4096 -> 32 bm tiles, 4 per XCD
  const int bn = sblk >> 2;
  const int wm = (w & 1) * 64, wn = (w >> 1) * (BN / 2);

  floatx4 acc[4][TN];
#pragma unroll
  for (int i = 0; i < 4; ++i)
#pragma unroll
    for (int j = 0; j < TN; ++j) acc[i][j] = (floatx4){0.f, 0.f, 0.f, 0.f};

  for (int k0 = 0; k0 < K; k0 += 64) {
    __syncthreads();
#pragma unroll
    for (int j = 0; j < 4; ++j) {  // A: 128 rows x 8 chunks = 1024 slots
      int i = j * 256 + tid;
      int row = i >> 3, c = (i & 7) ^ (row & 7);
      async16(A + (size_t)(bm * 128 + row) * K + k0 + c * 8, As + (j * 256 + w * 64) * 8);
    }
#pragma unroll
    for (int j = 0; j < BN / 32; ++j) {  // B: BN rows x 8 chunks
      int i = j * 256 + tid;
      int row = i >> 3, c = (i & 7) ^ (row & 7);
      async16(B + (size_t)(bn * BN + row) * K + k0 + c * 8, Bs + (j * 256 + w * 64) * 8);
    }
    __syncthreads();
    const int sw = l15 & 7;
#pragma unroll
    for (int ks = 0; ks < 2; ++ks) {
      short8 af[4], bf[TN];
#pragma unroll
      for (int t = 0; t < 4; ++t)
        af[t] = *(const short8*)(As + (wm + t * 16 + l15) * 64 + (((ks * 4 + l4) ^ sw)) * 8);
#pragma unroll
      for (int t = 0; t < TN; ++t)
        bf[t] = *(const short8*)(Bs + (wn + t * 16 + l15) * 64 + (((ks * 4 + l4) ^ sw)) * 8);
#pragma unroll
      for (int tm = 0; tm < 4; ++tm)
#pragma unroll
        for (int tn = 0; tn < TN; ++tn)
          acc[tm][tn] = TRANS ? MFMA16(bf[tn], af[tm], acc[tm][tn])
                              : MFMA16(af[tm], bf[tn], acc[tm][tn]);
    }
  }

  if (TRANS) {
    // acc holds transposed fragments: lane l15 -> row (A index), l4*4+r -> col (B index)
#pragma unroll
    for (int tn = 0; tn < TN; ++tn) {
      int colb = bn * BN + wn + tn * 16 + l4 * 4;
      float4 bv4 = *(const float4*)(bias + colb);
#pragma unroll
      for (int tm = 0; tm < 4; ++tm) {
        int row = bm * 128 + wm + tm * 16 + l15;
        float4 v;
        v.x = acc[tm][tn][0] + bv4.x;
        v.y = acc[tm][tn][1] + bv4.y;
        v.z = acc[tm][tn][2] + bv4.z;
        v.w = acc[tm][tn][3] + bv4.w;
        *(float4*)((float*)C + (size_t)row * N + colb) = v;
      }
    }
    return;
  }

#pragma unroll
  for (int tn = 0; tn < TN; ++tn) {
    int col = bn * BN + wn + tn * 16 + l15;
    float bv = bias[col];
    float sc = (col < scaleNend) ? scaleVal : 1.0f;
    if (!SPLITV || col < 2048) {
#pragma unroll
      for (int tm = 0; tm < 4; ++tm) {
        int row0 = bm * 128 + wm + tm * 16 + l4 * 4;
#pragma unroll
        for (int r = 0; r < 4; ++r) {
          float v = (acc[tm][tn][r] + bv) * sc;
          store_out(C + (size_t)(row0 + r) * N + col, v);
        }
      }
    } else {
      int hv = (col - 2048) >> 6, d = (col - 2048) & 63;
#pragma unroll
      for (int tm = 0; tm < 4; ++tm) {
        int row0 = bm * 128 + wm + tm * 16 + l4 * 4;
        int bb = row0 >> 11, s0 = row0 & 2047;
        union { unsigned long long ll; u16 s[4]; } o;
#pragma unroll
        for (int r = 0; r < 4; ++r) o.s[r] = f2bf(acc[tm][tn][r] + bv);
        // rows row0..row0+3 are consecutive (s&7) slots of one octet -> one 8B store
        size_t idx = ((((size_t)(bb * 16 + hv) * 128 + (s0 >> 4)) * 2 + ((s0 >> 3) & 1)) * 64 + d) * 8 +
                     (s0 & 7);
        *(unsigned long long*)(Vtc + idx) = o.ll;
      }
    }
  }
}

// ---------------- attention v3: r0 high-reuse tiling + shared-LDS Q -> 4 blocks/CU -------------
// TILING LESSON (r2): splitting waves 2q x 2k halved K/V reuse (MFMA:load 4:1 -> 2:1) and
// was 1.8x worse per-block despite full residency. Keep wave = 64q x 512keys (r0).
// REGISTER LESSON (r1): reported VGPR excludes AGPR accumulators; r0's true demand was
// 84 + 64 acc = 148 -> only 3 blocks/CU, with a 1-block/CU tail ~half the wall time.
// THIS ROUND: all 4 waves load IDENTICAL Q fragments (same 64 q-rows). Move Q to one
// shared 8KB LDS tile (source-chunk XOR-swizzle, same as GEMM staging; ds_read_b128 at
// the 8-cyc floor) and re-read 8 fragments per superstep: -32 VGPR -> ~118 combined
// <= 128 -> true 4 blocks/CU. Anti-LICM: Q pointer re-derived through an empty asm each
// superstep so the compiler cannot hoist the reads back into 32 registers.
// LDS: 4 wave regions x 2560 u16 (P[64][40]=2560 u16; reused post-loop as O-half[32][72]
// =2304 + l f32[64] at 2304..2431) + Q 4096 u16 = 28672 B/block; x4 = 114.7KB <= 160KB.
// O-combine split into two 32-row phases to fit the smaller region (3 barriers post-loop).
// [r9 lesson: NO manual register double-buffering -- compiler spills.]
__global__ __launch_bounds__(256, 4) void attn_kernel(const u16* __restrict__ QKV,
                                                      const u16* __restrict__ Vtc,
                                                      u16* __restrict__ Ob) {
  __shared__ __attribute__((aligned(16))) u16 lds[4 * 2560 + 4096];  // 28672 B
  const int tid = threadIdx.x;
  const int w = tid >> 6, lane = tid & 63;
  const int l15 = lane & 15, l4 = lane >> 4;
  const int lin = blockIdx.x;                 // 1024 blocks
  const int xcd = lin & 7, sblk = lin >> 3;   // sblk in [0,128)
  const int bh = xcd * 4 + (sblk & 3);        // 4 bh per XCD
  const int q0 = (sblk >> 2) * 64;            // 32 q-tiles of 64
  const int b = bh >> 4, h = bh & 15;

  u16* const Pw = lds + w * 2560;
  u16* const Qs = lds + 4 * 2560;

  // stage Q (64 rows x 8 chunks of 8 bf16) into shared LDS, source-swizzled c ^= row&7
#pragma unroll
  for (int j = 0; j < 2; ++j) {
    int i = j * 256 + tid;
    int row = i >> 3, c = (i & 7) ^ (row & 7);
    async16(QKV + (size_t)(b * 2048 + q0 + row) * 3072 + h * 64 + c * 8,
            Qs + (j * 256 + w * 64) * 8);
  }

  floatx4 Oacc[4][4];
#pragma unroll
  for (int i = 0; i < 4; ++i)
#pragma unroll
    for (int j = 0; j < 4; ++j) Oacc[i][j] = (floatx4){0.f, 0.f, 0.f, 0.f};
  float lpart[4] = {0.f, 0.f, 0.f, 0.f};

  const u16* const Kb = QKV + (size_t)(b * 2048) * 3072 + 1024 + h * 64;  // + key*3072
  const u16* const Vw = Vtc + (size_t)bh * 131072 + (size_t)w * 32768;    // wave's 512 keys
  const int kw0 = w * 512;
  const int swq = l15 & 7;

  __syncthreads();  // Q staged (sync drains the global_load_lds)

  for (int c = 0; c < 16; ++c) {  // 32-key supersteps
    const int key0 = kw0 + c * 32;
    // K fragments (A-operand): lane: key = key0 + t*16 + l15, d = s*32+l4*8
    short8 kf[2][2];
#pragma unroll
    for (int t = 0; t < 2; ++t)
#pragma unroll
      for (int s = 0; s < 2; ++s)
        kf[t][s] = *(const short8*)(Kb + (size_t)(key0 + t * 16 + l15) * 3072 + s * 32 + l4 * 8);
    // V fragments (B-operand): lane: d = td*16+l15, keys l4*8..+8
    short8 vf[4];
#pragma unroll
    for (int td = 0; td < 4; ++td)
      vf[td] = *(const short8*)(Vw + (size_t)c * 2048 + l4 * 512 + (td * 16 + l15) * 8);

    // Q fragments from shared LDS each superstep (anti-LICM: opaque pointer per iter)
    const u16* Qi = Qs;
    asm volatile("" : "+v"(Qi));
    short8 qf[4][2];
#pragma unroll
    for (int tq = 0; tq < 4; ++tq)
#pragma unroll
      for (int s = 0; s < 2; ++s)
        qf[tq][s] = *(const short8*)(Qi + (tq * 16 + l15) * 64 + ((s * 4 + l4) ^ swq) * 8);

    // S^T: C[key16][q16]; row=key=l4*4+r, col=q=l15
#pragma unroll
    for (int t = 0; t < 2; ++t)
#pragma unroll
      for (int tq = 0; tq < 4; ++tq) {
        floatx4 s = (floatx4){0.f, 0.f, 0.f, 0.f};
        s = MFMA16(kf[t][0], qf[tq][0], s);
        s = MFMA16(kf[t][1], qf[tq][1], s);
        float p0 = fexp2(s[0]), p1 = fexp2(s[1]), p2 = fexp2(s[2]), p3 = fexp2(s[3]);
        lpart[tq] += (p0 + p1) + (p2 + p3);
        unsigned lo = pk2(p1, p0), hi = pk2(p3, p2);
        *(unsigned long long*)(Pw + (size_t)(tq * 16 + l15) * 40 + t * 16 + l4 * 4) =
            ((unsigned long long)hi << 32) | lo;
      }

    // PV: O[q][d] += P[q][k32] * V[k32][d]
    short8 pf[4];
#pragma unroll
    for (int tq = 0; tq < 4; ++tq)
      pf[tq] = *(const short8*)(Pw + (size_t)(tq * 16 + l15) * 40 + l4 * 8);
#pragma unroll
    for (int td = 0; td < 4; ++td)
#pragma unroll
      for (int tq = 0; tq < 4; ++tq) Oacc[tq][td] = MFMA16(pf[tq], vf[td], Oacc[tq][td]);
  }

  // per-wave l reduction across l4 key-groups (full 512-key sums per q)
  float lr[4];
#pragma unroll
  for (int tq = 0; tq < 4; ++tq) {
    float l = lpart[tq];
    l += __shfl_xor(l, 16);
    l += __shfl_xor(l, 32);
    lr[tq] = l;
  }

  // ---- O combine, two 32-row phases (region = [32][72] bf16 + l f32[64] at 2304) ----
  // Phase A: rows 0..31 (tq 0,1). l for ALL 64 rows written once here.
  if (l4 == 0) {
    float* Lw = (float*)(Pw + 2304);
#pragma unroll
    for (int tq = 0; tq < 4; ++tq) Lw[tq * 16 + l15] = lr[tq];
  }
#pragma unroll
  for (int tq = 0; tq < 2; ++tq)
#pragma unroll
    for (int td = 0; td < 4; ++td)
#pragma unroll
      for (int r = 0; r < 4; ++r)
        Pw[(size_t)(tq * 16 + l4 * 4 + r) * 72 + td * 16 + l15] = f2bf(Oacc[tq][td][r]);
  __syncthreads();
  {
    int row = tid >> 3, c0 = (tid & 7) * 8;  // 32 rows x 8 cols/thread
    float acc[8];
#pragma unroll
    for (int j = 0; j < 8; ++j) acc[j] = 0.f;
    float lsum = 0.f;
#pragma unroll
    for (int wv = 0; wv < 4; ++wv) {
      const u16* R = lds + wv * 2560;
      lsum += ((const float*)(R + 2304))[row];
      U128u x1;
      x1.q = *(const uint4*)(R + (size_t)row * 72 + c0);
#pragma unroll
      for (int j = 0; j < 8; ++j) acc[j] += bf2f(x1.s[j]);
    }
    float inv = 1.0f / lsum;
    U128u o1;
#pragma unroll
    for (int j = 0; j < 8; ++j) o1.s[j] = f2bf(acc[j] * inv);
    *(uint4*)(Ob + (size_t)(b * 2048 + q0 + row) * 1024 + h * 64 + c0) = o1.q;
  }
  __syncthreads();
  // Phase B: rows 32..63 (tq 2,3)
#pragma unroll
  for (int tq = 2; tq < 4; ++tq)
#pragma unroll
    for (int td = 0; td < 4; ++td)
#pragma unroll
      for (int r = 0; r < 4; ++r)
        Pw[(size_t)((tq - 2) * 16 + l4 * 4 + r) * 72 + td * 16 + l15] = f2bf(Oacc[tq][td][r]);
  __syncthreads();
  {
    int row = tid >> 3, c0 = (tid & 7) * 8;
    float acc[8];
#pragma unroll
    for (int j = 0; j < 8; ++j) acc[j] = 0.f;
    float lsum = 0.f;
#pragma unroll
    for (int wv = 0; wv < 4; ++wv) {
      const u16* R = lds + wv * 2560;
      lsum += ((const float*)(R + 2304))[32 + row];
      U128u x1;
      x1.q = *(const uint4*)(R + (size_t)row * 72 + c0);
#pragma unroll
      for (int j = 0; j < 8; ++j) acc[j] += bf2f(x1.s[j]);
    }
    float inv = 1.0f / lsum;
    U128u o1;
#pragma unroll
    for (int j = 0; j < 8; ++j) o1.s[j] = f2bf(acc[j] * inv);
    *(uint4*)(Ob + (size_t)(b * 2048 + q0 + 32 + row) * 1024 + h * 64 + c0) = o1.q;
  }
}

// ---------------- launch ----------------

extern "C" void kernel_launch(void* const* d_in, const int* in_sizes, int n_in,
                              void* d_out, int out_size, void* d_ws, size_t ws_size,
                              hipStream_t stream) {
  const float* x  = (const float*)d_in[0];
  const float* Wq = (const float*)d_in[1];
  const float* bq = (const float*)d_in[2];
  const float* Wk = (const float*)d_in[3];
  const float* bk = (const float*)d_in[4];
  const float* Wv = (const float*)d_in[5];
  const float* bv = (const float*)d_in[6];
  const float* Wo = (const float*)d_in[7];
  const float* bo = (const float*)d_in[8];

  char* p = (char*)d_ws;
  u16* Xb   = (u16*)p; p += (size_t)4096 * 1024 * 2;   // x bf16
  u16* Wt   = (u16*)p; p += (size_t)3072 * 1024 * 2;   // W_all^T bf16 [n][d]
  u16* QKV  = (u16*)p; p += (size_t)4096 * 3072 * 2;   // [token][3072] bf16; Q pre-scaled, V third unused
  u16* Vtc  = (u16*)p; p += (size_t)32 * 128 * 2 * 64 * 8 * 2;  // V chunked: [bh][v][o][d][k8]
  u16* Ob   = (u16*)p; p += (size_t)4096 * 1024 * 2;   // attention out bf16 (normalized)
  u16* Wob  = (u16*)p; p += (size_t)1024 * 1024 * 2;   // Wo bf16 [e][d]
  float* ball = (float*)p; p += 3072 * sizeof(float);

  const float qscale = 0.125f * 1.4426950408889634f;  // (1/sqrt(64)) * log2(e)

  prep_all<<<8192, 256, 0, stream>>>(x, Wo, Wq, bq, Wk, bk, Wv, bv, Xb, Wob, Wt, ball);
  // QKV: BN=96 -> 32x32 = 1024 blocks = 4 blocks/CU (occupancy; was 768 = 3/CU)
  gemm_bt<96, true, false, u16><<<1024, 256, 0, stream>>>(Xb, Wt, ball, QKV, Vtc,
                                                          4096, 3072, 1024, 1024, qscale);
  attn_kernel<<<1024, 256, 0, stream>>>(QKV, Vtc, Ob);
  // out-proj: TRANS epilogue -> float4 stores
  gemm_bt<64, false, true, float><<<512, 256, 0, stream>>>(Ob, Wob, bo, (float*)d_out, nullptr,
                                                           4096, 1024, 1024, 0, 1.0f);
}

// Round 4
// 272.147 us; speedup vs baseline: 1.0853x; 1.0853x over previous
//
#include <hip/hip_runtime.h>
#include <hip/hip_bf16.h>

typedef unsigned short u16;
typedef short short8 __attribute__((ext_vector_type(8)));
typedef float floatx4 __attribute__((ext_vector_type(4)));

#define MFMA16(a, b, c) __builtin_amdgcn_mfma_f32_16x16x32_bf16((a), (b), (c), 0, 0, 0)

union U128u { uint4 q; u16 s[8]; };

__device__ __forceinline__ u16 f2bf(float f) {
  union { float f; unsigned u; } v; v.f = f;
  unsigned r = v.u + 0x7fffu + ((v.u >> 16) & 1u);
  return (u16)(r >> 16);
}

__device__ __forceinline__ float bf2f(u16 s) {
  union { unsigned u; float f; } v; v.u = ((unsigned)s) << 16;
  return v.f;
}

// pack two f32 -> bf16x2 (round-half-up) with one v_perm (attn P only)
__device__ __forceinline__ unsigned pk2(float hi, float lo) {
  union { float f; unsigned u; } a, b;
  a.f = hi; b.f = lo;
  return __builtin_amdgcn_perm(a.u + 0x8000u, b.u + 0x8000u, 0x07060302u);
}

__device__ __forceinline__ float fexp2(float x) {
#if __has_builtin(__builtin_amdgcn_exp2f)
  return __builtin_amdgcn_exp2f(x);
#else
  return exp2f(x);
#endif
}

// async global->LDS, 16B per lane. lds pointer must be wave-uniform.
__device__ __forceinline__ void async16(const u16* g, u16* l) {
  __builtin_amdgcn_global_load_lds(
      (const __attribute__((address_space(1))) unsigned int*)g,
      (__attribute__((address_space(3))) unsigned int*)l, 16, 0, 0);
}

// ---------------- merged prep: cast x, cast Wo, repack Wqkv + biases ----------------

__global__ __launch_bounds__(256) void prep_all(
    const float* __restrict__ x, const float* __restrict__ Wo,
    const float* __restrict__ Wq, const float* __restrict__ bq,
    const float* __restrict__ Wk, const float* __restrict__ bk,
    const float* __restrict__ Wv, const float* __restrict__ bv,
    u16* __restrict__ Xb, u16* __restrict__ Wob,
    u16* __restrict__ Wt, float* __restrict__ ball) {
  int bid = blockIdx.x;
  int tid = threadIdx.x;
  if (bid < 5120) {
    // cast: blocks [0,4096) -> x (1048576 float4), [4096,5120) -> Wo (262144 float4)
    const float* src = bid < 4096 ? x : Wo;
    u16* dst = bid < 4096 ? Xb : Wob;
    int i = (bid < 4096 ? bid : bid - 4096) * 256 + tid;
    float4 v = ((const float4*)src)[i];
    union { unsigned long long ll; u16 s[4]; } o;
    o.s[0] = f2bf(v.x); o.s[1] = f2bf(v.y); o.s[2] = f2bf(v.z); o.s[3] = f2bf(v.w);
    ((unsigned long long*)dst)[i] = o.ll;
    return;
  }
  int id = (bid - 5120) * 256 + tid;  // 786432 total
  int kk4 = id & 15;
  int d = (id >> 4) & 1023;
  int h = (id >> 14) & 15;
  int wsel = id >> 18;
  const float* W = wsel == 0 ? Wq : (wsel == 1 ? Wk : Wv);
  float4 v = *(const float4*)(W + ((size_t)(h * 1024 + d)) * 64 + kk4 * 4);
  int nb = wsel * 1024 + h * 64 + kk4 * 4;
  Wt[(size_t)(nb + 0) * 1024 + d] = f2bf(v.x);
  Wt[(size_t)(nb + 1) * 1024 + d] = f2bf(v.y);
  Wt[(size_t)(nb + 2) * 1024 + d] = f2bf(v.z);
  Wt[(size_t)(nb + 3) * 1024 + d] = f2bf(v.w);
  if (id < 3072) {
    int ws2 = id >> 10, hk = id & 1023;
    const float* bsrc = ws2 == 0 ? bq : (ws2 == 1 ? bk : bv);
    ball[id] = bsrc[hk];
  }
}

// ---------------- GEMM: C[M,N] = A[M,K] * B^T (B stored [N,K]) + bias, opt scale --------------

__device__ __forceinline__ void store_out(u16* p, float v) { *p = f2bf(v); }
__device__ __forceinline__ void store_out(float* p, float v) { *p = v; }

template <int BN, bool SPLITV, bool TRANS, typename OutT>
__global__ __launch_bounds__(256, 4) void gemm_bt(
    const u16* __restrict__ A, const u16* __restrict__ B,
    const float* __restrict__ bias, OutT* __restrict__ C,
    u16* __restrict__ Vtc,
    int M, int N, int K, int scaleNend, float scaleVal) {
  constexpr int TN = BN / 32;  // n-tiles per wave
  __shared__ __attribute__((aligned(16))) u16 As[128 * 64];
  __shared__ __attribute__((aligned(16))) u16 Bs[BN * 64];
  const int tid = threadIdx.x;
  const int w = tid >> 6, lane = tid & 63;
  const int l15 = lane & 15, l4 = lane >> 4;
  const int lin = blockIdx.x;
  const int xcd = lin & 7, sblk = lin >> 3;
  const int bm = xcd * 4 + (sblk & 3);   // M=4096 -> 32 bm tiles, 4 per XCD
  const int bn = sblk >> 2;
  const int wm = (w & 1) * 64, wn = (w >> 1) * (BN / 2);

  floatx4 acc[4][TN];
#pragma unroll
  for (int i = 0; i < 4; ++i)
#pragma unroll
    for (int j = 0; j < TN; ++j) acc[i][j] = (floatx4){0.f, 0.f, 0.f, 0.f};

  for (int k0 = 0; k0 < K; k0 += 64) {
    __syncthreads();
#pragma unroll
    for (int j = 0; j < 4; ++j) {  // A: 128 rows x 8 chunks = 1024 slots
      int i = j * 256 + tid;
      int row = i >> 3, c = (i & 7) ^ (row & 7);
      async16(A + (size_t)(bm * 128 + row) * K + k0 + c * 8, As + (j * 256 + w * 64) * 8);
    }
#pragma unroll
    for (int j = 0; j < BN / 32; ++j) {  // B: BN rows x 8 chunks
      int i = j * 256 + tid;
      int row = i >> 3, c = (i & 7) ^ (row & 7);
      async16(B + (size_t)(bn * BN + row) * K + k0 + c * 8, Bs + (j * 256 + w * 64) * 8);
    }
    __syncthreads();
    const int sw = l15 & 7;
#pragma unroll
    for (int ks = 0; ks < 2; ++ks) {
      short8 af[4], bf[TN];
#pragma unroll
      for (int t = 0; t < 4; ++t)
        af[t] = *(const short8*)(As + (wm + t * 16 + l15) * 64 + (((ks * 4 + l4) ^ sw)) * 8);
#pragma unroll
      for (int t = 0; t < TN; ++t)
        bf[t] = *(const short8*)(Bs + (wn + t * 16 + l15) * 64 + (((ks * 4 + l4) ^ sw)) * 8);
#pragma unroll
      for (int tm = 0; tm < 4; ++tm)
#pragma unroll
        for (int tn = 0; tn < TN; ++tn)
          acc[tm][tn] = TRANS ? MFMA16(bf[tn], af[tm], acc[tm][tn])
                              : MFMA16(af[tm], bf[tn], acc[tm][tn]);
    }
  }

  if (TRANS) {
    // acc holds transposed fragments: lane l15 -> row (A index), l4*4+r -> col (B index)
#pragma unroll
    for (int tn = 0; tn < TN; ++tn) {
      int colb = bn * BN + wn + tn * 16 + l4 * 4;
      float4 bv4 = *(const float4*)(bias + colb);
#pragma unroll
      for (int tm = 0; tm < 4; ++tm) {
        int row = bm * 128 + wm + tm * 16 + l15;
        float4 v;
        v.x = acc[tm][tn][0] + bv4.x;
        v.y = acc[tm][tn][1] + bv4.y;
        v.z = acc[tm][tn][2] + bv4.z;
        v.w = acc[tm][tn][3] + bv4.w;
        *(float4*)((float*)C + (size_t)row * N + colb) = v;
      }
    }
    return;
  }

#pragma unroll
  for (int tn = 0; tn < TN; ++tn) {
    int col = bn * BN + wn + tn * 16 + l15;
    float bv = bias[col];
    float sc = (col < scaleNend) ? scaleVal : 1.0f;
    if (!SPLITV || col < 2048) {
#pragma unroll
      for (int tm = 0; tm < 4; ++tm) {
        int row0 = bm * 128 + wm + tm * 16 + l4 * 4;
#pragma unroll
        for (int r = 0; r < 4; ++r) {
          float v = (acc[tm][tn][r] + bv) * sc;
          store_out(C + (size_t)(row0 + r) * N + col, v);
        }
      }
    } else {
      int hv = (col - 2048) >> 6, d = (col - 2048) & 63;
#pragma unroll
      for (int tm = 0; tm < 4; ++tm) {
        int row0 = bm * 128 + wm + tm * 16 + l4 * 4;
        int bb = row0 >> 11, s0 = row0 & 2047;
        union { unsigned long long ll; u16 s[4]; } o;
#pragma unroll
        for (int r = 0; r < 4; ++r) o.s[r] = f2bf(acc[tm][tn][r] + bv);
        // rows row0..row0+3 are consecutive (s&7) slots of one octet -> one 8B store
        size_t idx = ((((size_t)(bb * 16 + hv) * 128 + (s0 >> 4)) * 2 + ((s0 >> 3) & 1)) * 64 + d) * 8 +
                     (s0 & 7);
        *(unsigned long long*)(Vtc + idx) = o.ll;
      }
    }
  }
}

// ---------------- attention v4: r0 tiling + LDS Q + PER-TQ SECTIONED S^T -> 4 blocks/CU --------
// TILING LESSON (r2): 2q x 2k wave split halves K/V reuse; 1.8x worse. Keep 64q x 512k/wave.
// SPILL LESSON (r1): reported VGPR excludes AGPR accumulators; true demand 148 at (256,4)
// spilled Oacc (330 MB scratch). SPILL LESSON (r3): Q-in-LDS alone does NOT cut the peak --
// the unrolled superstep still groups all 8 qf ds_reads (peak 150, spilled Oacc, 500 MB).
// THIS ROUND: S^T is four PER-TQ SECTIONS. Each section: fresh opaque Q pointer (kills
// LICM and CSE -- address is unknowable across sections), read ONLY 2 qf frags (8 regs),
// 4 MFMAs, exp/pack, P store, then sched_barrier(0) so the scheduler CANNOT merge qf
// reads across sections (r3's failure). PV reads pf per-tq transiently too.
// Peak live = Oacc 64 + kf 16 + vf 16 + qf 8 + temps ~12 + addr ~10 = ~126 <= 128.
// Per-section ds_read latency lands on the wave's critical path; 16 waves/CU cover it --
// that is what the occupancy buys (r0 tail proved per-tile time is concurrency-independent,
// so throughput scales with resident blocks: 4/CU in one phase ~= r0's 70 us / 2).
// GATE: FETCH ~12.5 MB / WRITE ~8 MB = no spill. If ballooned, retreat to (256,3) r0.
// LDS: 4 x 2560 u16 P regions + Q 4096 u16 = 28672 B; x4 blocks = 114.7 KB <= 160 KB.
__global__ __launch_bounds__(256, 4) void attn_kernel(const u16* __restrict__ QKV,
                                                      const u16* __restrict__ Vtc,
                                                      u16* __restrict__ Ob) {
  __shared__ __attribute__((aligned(16))) u16 lds[4 * 2560 + 4096];  // 28672 B
  const int tid = threadIdx.x;
  const int w = tid >> 6, lane = tid & 63;
  const int l15 = lane & 15, l4 = lane >> 4;
  const int lin = blockIdx.x;                 // 1024 blocks
  const int xcd = lin & 7, sblk = lin >> 3;   // sblk in [0,128)
  const int bh = xcd * 4 + (sblk & 3);        // 4 bh per XCD
  const int q0 = (sblk >> 2) * 64;            // 32 q-tiles of 64
  const int b = bh >> 4, h = bh & 15;

  u16* const Pw = lds + w * 2560;
  u16* const Qs = lds + 4 * 2560;

  // stage Q (64 rows x 8 chunks of 8 bf16) into shared LDS, source-swizzled c ^= row&7
#pragma unroll
  for (int j = 0; j < 2; ++j) {
    int i = j * 256 + tid;
    int row = i >> 3, c = (i & 7) ^ (row & 7);
    async16(QKV + (size_t)(b * 2048 + q0 + row) * 3072 + h * 64 + c * 8,
            Qs + (j * 256 + w * 64) * 8);
  }

  floatx4 Oacc[4][4];
#pragma unroll
  for (int i = 0; i < 4; ++i)
#pragma unroll
    for (int j = 0; j < 4; ++j) Oacc[i][j] = (floatx4){0.f, 0.f, 0.f, 0.f};
  float lpart[4] = {0.f, 0.f, 0.f, 0.f};

  const u16* const Kb = QKV + (size_t)(b * 2048) * 3072 + 1024 + h * 64;  // + key*3072
  const u16* const Vw = Vtc + (size_t)bh * 131072 + (size_t)w * 32768;    // wave's 512 keys
  const int kw0 = w * 512;
  const int swq = l15 & 7;

  __syncthreads();  // Q staged (sync drains the global_load_lds)

  for (int c = 0; c < 16; ++c) {  // 32-key supersteps
    const int key0 = kw0 + c * 32;
    // K fragments (A-operand): lane: key = key0 + t*16 + l15, d = s*32+l4*8
    short8 kf[2][2];
#pragma unroll
    for (int t = 0; t < 2; ++t)
#pragma unroll
      for (int s = 0; s < 2; ++s)
        kf[t][s] = *(const short8*)(Kb + (size_t)(key0 + t * 16 + l15) * 3072 + s * 32 + l4 * 8);
    // V fragments (B-operand): lane: d = td*16+l15, keys l4*8..+8
    short8 vf[4];
#pragma unroll
    for (int td = 0; td < 4; ++td)
      vf[td] = *(const short8*)(Vw + (size_t)c * 2048 + l4 * 512 + (td * 16 + l15) * 8);

    // S^T in four per-tq sections; each holds only its own 2 qf fragments live.
#pragma unroll
    for (int tq = 0; tq < 4; ++tq) {
      const u16* Qtq = Qs;
      asm volatile("" : "+v"(Qtq));  // opaque per section: no LICM, no cross-section CSE
      short8 q0f = *(const short8*)(Qtq + (tq * 16 + l15) * 64 + ((0 + l4) ^ swq) * 8);
      short8 q1f = *(const short8*)(Qtq + (tq * 16 + l15) * 64 + ((4 + l4) ^ swq) * 8);
      floatx4 s0 = (floatx4){0.f, 0.f, 0.f, 0.f};
      floatx4 s1 = (floatx4){0.f, 0.f, 0.f, 0.f};
      s0 = MFMA16(kf[0][0], q0f, s0);
      s0 = MFMA16(kf[0][1], q1f, s0);
      s1 = MFMA16(kf[1][0], q0f, s1);
      s1 = MFMA16(kf[1][1], q1f, s1);
      float p0 = fexp2(s0[0]), p1 = fexp2(s0[1]), p2 = fexp2(s0[2]), p3 = fexp2(s0[3]);
      float r0 = fexp2(s1[0]), r1 = fexp2(s1[1]), r2 = fexp2(s1[2]), r3 = fexp2(s1[3]);
      lpart[tq] += ((p0 + p1) + (p2 + p3)) + ((r0 + r1) + (r2 + r3));
      unsigned lo0 = pk2(p1, p0), hi0 = pk2(p3, p2);
      unsigned lo1 = pk2(r1, r0), hi1 = pk2(r3, r2);
      *(unsigned long long*)(Pw + (size_t)(tq * 16 + l15) * 40 + l4 * 4) =
          ((unsigned long long)hi0 << 32) | lo0;
      *(unsigned long long*)(Pw + (size_t)(tq * 16 + l15) * 40 + 16 + l4 * 4) =
          ((unsigned long long)hi1 << 32) | lo1;
      __builtin_amdgcn_sched_barrier(0);  // pin section: qf reads cannot merge across tq
    }

    // PV: O[q][d] += P[q][k32] * V[k32][d]; pf transient per tq
#pragma unroll
    for (int tq = 0; tq < 4; ++tq) {
      short8 pf = *(const short8*)(Pw + (size_t)(tq * 16 + l15) * 40 + l4 * 8);
#pragma unroll
      for (int td = 0; td < 4; ++td) Oacc[tq][td] = MFMA16(pf, vf[td], Oacc[tq][td]);
    }
  }

  // per-wave l reduction across l4 key-groups (full 512-key sums per q)
  float lr[4];
#pragma unroll
  for (int tq = 0; tq < 4; ++tq) {
    float l = lpart[tq];
    l += __shfl_xor(l, 16);
    l += __shfl_xor(l, 32);
    lr[tq] = l;
  }

  // ---- O combine, two 32-row phases (region = [32][72] bf16 + l f32[64] at 2304) ----
  // Phase A: rows 0..31 (tq 0,1). l for ALL 64 rows written once here.
  if (l4 == 0) {
    float* Lw = (float*)(Pw + 2304);
#pragma unroll
    for (int tq = 0; tq < 4; ++tq) Lw[tq * 16 + l15] = lr[tq];
  }
#pragma unroll
  for (int tq = 0; tq < 2; ++tq)
#pragma unroll
    for (int td = 0; td < 4; ++td)
#pragma unroll
      for (int r = 0; r < 4; ++r)
        Pw[(size_t)(tq * 16 + l4 * 4 + r) * 72 + td * 16 + l15] = f2bf(Oacc[tq][td][r]);
  __syncthreads();
  {
    int row = tid >> 3, c0 = (tid & 7) * 8;  // 32 rows x 8 cols/thread
    float acc[8];
#pragma unroll
    for (int j = 0; j < 8; ++j) acc[j] = 0.f;
    float lsum = 0.f;
#pragma unroll
    for (int wv = 0; wv < 4; ++wv) {
      const u16* R = lds + wv * 2560;
      lsum += ((const float*)(R + 2304))[row];
      U128u x1;
      x1.q = *(const uint4*)(R + (size_t)row * 72 + c0);
#pragma unroll
      for (int j = 0; j < 8; ++j) acc[j] += bf2f(x1.s[j]);
    }
    float inv = 1.0f / lsum;
    U128u o1;
#pragma unroll
    for (int j = 0; j < 8; ++j) o1.s[j] = f2bf(acc[j] * inv);
    *(uint4*)(Ob + (size_t)(b * 2048 + q0 + row) * 1024 + h * 64 + c0) = o1.q;
  }
  __syncthreads();
  // Phase B: rows 32..63 (tq 2,3)
#pragma unroll
  for (int tq = 2; tq < 4; ++tq)
#pragma unroll
    for (int td = 0; td < 4; ++td)
#pragma unroll
      for (int r = 0; r < 4; ++r)
        Pw[(size_t)((tq - 2) * 16 + l4 * 4 + r) * 72 + td * 16 + l15] = f2bf(Oacc[tq][td][r]);
  __syncthreads();
  {
    int row = tid >> 3, c0 = (tid & 7) * 8;
    float acc[8];
#pragma unroll
    for (int j = 0; j < 8; ++j) acc[j] = 0.f;
    float lsum = 0.f;
#pragma unroll
    for (int wv = 0; wv < 4; ++wv) {
      const u16* R = lds + wv * 2560;
      lsum += ((const float*)(R + 2304))[32 + row];
      U128u x1;
      x1.q = *(const uint4*)(R + (size_t)row * 72 + c0);
#pragma unroll
      for (int j = 0; j < 8; ++j) acc[j] += bf2f(x1.s[j]);
    }
    float inv = 1.0f / lsum;
    U128u o1;
#pragma unroll
    for (int j = 0; j < 8; ++j) o1.s[j] = f2bf(acc[j] * inv);
    *(uint4*)(Ob + (size_t)(b * 2048 + q0 + 32 + row) * 1024 + h * 64 + c0) = o1.q;
  }
}

// ---------------- launch ----------------

extern "C" void kernel_launch(void* const* d_in, const int* in_sizes, int n_in,
                              void* d_out, int out_size, void* d_ws, size_t ws_size,
                              hipStream_t stream) {
  const float* x  = (const float*)d_in[0];
  const float* Wq = (const float*)d_in[1];
  const float* bq = (const float*)d_in[2];
  const float* Wk = (const float*)d_in[3];
  const float* bk = (const float*)d_in[4];
  const float* Wv = (const float*)d_in[5];
  const float* bv = (const float*)d_in[6];
  const float* Wo = (const float*)d_in[7];
  const float* bo = (const float*)d_in[8];

  char* p = (char*)d_ws;
  u16* Xb   = (u16*)p; p += (size_t)4096 * 1024 * 2;   // x bf16
  u16* Wt   = (u16*)p; p += (size_t)3072 * 1024 * 2;   // W_all^T bf16 [n][d]
  u16* QKV  = (u16*)p; p += (size_t)4096 * 3072 * 2;   // [token][3072] bf16; Q pre-scaled, V third unused
  u16* Vtc  = (u16*)p; p += (size_t)32 * 128 * 2 * 64 * 8 * 2;  // V chunked: [bh][v][o][d][k8]
  u16* Ob   = (u16*)p; p += (size_t)4096 * 1024 * 2;   // attention out bf16 (normalized)
  u16* Wob  = (u16*)p; p += (size_t)1024 * 1024 * 2;   // Wo bf16 [e][d]
  float* ball = (float*)p; p += 3072 * sizeof(float);

  const float qscale = 0.125f * 1.4426950408889634f;  // (1/sqrt(64)) * log2(e)

  prep_all<<<8192, 256, 0, stream>>>(x, Wo, Wq, bq, Wk, bk, Wv, bv, Xb, Wob, Wt, ball);
  // QKV: BN=96 -> 32x32 = 1024 blocks = 4 blocks/CU (occupancy; was 768 = 3/CU)
  gemm_bt<96, true, false, u16><<<1024, 256, 0, stream>>>(Xb, Wt, ball, QKV, Vtc,
                                                          4096, 3072, 1024, 1024, qscale);
  attn_kernel<<<1024, 256, 0, stream>>>(QKV, Vtc, Ob);
  // out-proj: TRANS epilogue -> float4 stores
  gemm_bt<64, false, true, float><<<512, 256, 0, stream>>>(Ob, Wob, bo, (float*)d_out, nullptr,
                                                           4096, 1024, 1024, 0, 1.0f);
}

// Round 5
// 200.263 us; speedup vs baseline: 1.4748x; 1.3589x over previous
//
#include <hip/hip_runtime.h>
#include <hip/hip_bf16.h>

typedef unsigned short u16;
typedef short short8 __attribute__((ext_vector_type(8)));
typedef float floatx4 __attribute__((ext_vector_type(4)));

#define MFMA16(a, b, c) __builtin_amdgcn_mfma_f32_16x16x32_bf16((a), (b), (c), 0, 0, 0)

union U128u { uint4 q; u16 s[8]; };

__device__ __forceinline__ u16 f2bf(float f) {
  union { float f; unsigned u; } v; v.f = f;
  unsigned r = v.u + 0x7fffu + ((v.u >> 16) & 1u);
  return (u16)(r >> 16);
}

__device__ __forceinline__ float bf2f(u16 s) {
  union { unsigned u; float f; } v; v.u = ((unsigned)s) << 16;
  return v.f;
}

// pack two f32 -> bf16x2 (round-half-up) with one v_perm (attn P only)
__device__ __forceinline__ unsigned pk2(float hi, float lo) {
  union { float f; unsigned u; } a, b;
  a.f = hi; b.f = lo;
  return __builtin_amdgcn_perm(a.u + 0x8000u, b.u + 0x8000u, 0x07060302u);
}

__device__ __forceinline__ float fexp2(float x) {
#if __has_builtin(__builtin_amdgcn_exp2f)
  return __builtin_amdgcn_exp2f(x);
#else
  return exp2f(x);
#endif
}

// async global->LDS, 16B per lane. lds pointer must be wave-uniform. (GEMMs only.)
__device__ __forceinline__ void async16(const u16* g, u16* l) {
  __builtin_amdgcn_global_load_lds(
      (const __attribute__((address_space(1))) unsigned int*)g,
      (__attribute__((address_space(3))) unsigned int*)l, 16, 0, 0);
}

// ---------------- merged prep: cast x, cast Wo, repack Wqkv + biases ----------------

__global__ __launch_bounds__(256) void prep_all(
    const float* __restrict__ x, const float* __restrict__ Wo,
    const float* __restrict__ Wq, const float* __restrict__ bq,
    const float* __restrict__ Wk, const float* __restrict__ bk,
    const float* __restrict__ Wv, const float* __restrict__ bv,
    u16* __restrict__ Xb, u16* __restrict__ Wob,
    u16* __restrict__ Wt, float* __restrict__ ball) {
  int bid = blockIdx.x;
  int tid = threadIdx.x;
  if (bid < 5120) {
    // cast: blocks [0,4096) -> x (1048576 float4), [4096,5120) -> Wo (262144 float4)
    const float* src = bid < 4096 ? x : Wo;
    u16* dst = bid < 4096 ? Xb : Wob;
    int i = (bid < 4096 ? bid : bid - 4096) * 256 + tid;
    float4 v = ((const float4*)src)[i];
    union { unsigned long long ll; u16 s[4]; } o;
    o.s[0] = f2bf(v.x); o.s[1] = f2bf(v.y); o.s[2] = f2bf(v.z); o.s[3] = f2bf(v.w);
    ((unsigned long long*)dst)[i] = o.ll;
    return;
  }
  int id = (bid - 5120) * 256 + tid;  // 786432 total
  int kk4 = id & 15;
  int d = (id >> 4) & 1023;
  int h = (id >> 14) & 15;
  int wsel = id >> 18;
  const float* W = wsel == 0 ? Wq : (wsel == 1 ? Wk : Wv);
  float4 v = *(const float4*)(W + ((size_t)(h * 1024 + d)) * 64 + kk4 * 4);
  int nb = wsel * 1024 + h * 64 + kk4 * 4;
  Wt[(size_t)(nb + 0) * 1024 + d] = f2bf(v.x);
  Wt[(size_t)(nb + 1) * 1024 + d] = f2bf(v.y);
  Wt[(size_t)(nb + 2) * 1024 + d] = f2bf(v.z);
  Wt[(size_t)(nb + 3) * 1024 + d] = f2bf(v.w);
  if (id < 3072) {
    int ws2 = id >> 10, hk = id & 1023;
    const float* bsrc = ws2 == 0 ? bq : (ws2 == 1 ? bk : bv);
    ball[id] = bsrc[hk];
  }
}

// ---------------- GEMM: C[M,N] = A[M,K] * B^T (B stored [N,K]) + bias, opt scale --------------

__device__ __forceinline__ void store_out(u16* p, float v) { *p = f2bf(v); }
__device__ __forceinline__ void store_out(float* p, float v) { *p = v; }

template <int BN, bool SPLITV, bool TRANS, typename OutT>
__global__ __launch_bounds__(256, 4) void gemm_bt(
    const u16* __restrict__ A, const u16* __restrict__ B,
    const float* __restrict__ bias, OutT* __restrict__ C,
    u16* __restrict__ Vtc,
    int M, int N, int K, int scaleNend, float scaleVal) {
  constexpr int TN = BN / 32;  // n-tiles per wave
  __shared__ __attribute__((aligned(16))) u16 As[128 * 64];
  __shared__ __attribute__((aligned(16))) u16 Bs[BN * 64];
  const int tid = threadIdx.x;
  const int w = tid >> 6, lane = tid & 63;
  const int l15 = lane & 15, l4 = lane >> 4;
  const int lin = blockIdx.x;
  const int xcd = lin & 7, sblk = lin >> 3;
  const int bm = xcd * 4 + (sblk & 3);   // M=4096 -> 32 bm tiles, 4 per XCD
  const int bn = sblk >> 2;
  const int wm = (w & 1) * 64, wn = (w >> 1) * (BN / 2);

  floatx4 acc[4][TN];
#pragma unroll
  for (int i = 0; i < 4; ++i)
#pragma unroll
    for (int j = 0; j < TN; ++j) acc[i][j] = (floatx4){0.f, 0.f, 0.f, 0.f};

  for (int k0 = 0; k0 < K; k0 += 64) {
    __syncthreads();
#pragma unroll
    for (int j = 0; j < 4; ++j) {  // A: 128 rows x 8 chunks = 1024 slots
      int i = j * 256 + tid;
      int row = i >> 3, c = (i & 7) ^ (row & 7);
      async16(A + (size_t)(bm * 128 + row) * K + k0 + c * 8, As + (j * 256 + w * 64) * 8);
    }
#pragma unroll
    for (int j = 0; j < BN / 32; ++j) {  // B: BN rows x 8 chunks
      int i = j * 256 + tid;
      int row = i >> 3, c = (i & 7) ^ (row & 7);
      async16(B + (size_t)(bn * BN + row) * K + k0 + c * 8, Bs + (j * 256 + w * 64) * 8);
    }
    __syncthreads();
    const int sw = l15 & 7;
#pragma unroll
    for (int ks = 0; ks < 2; ++ks) {
      short8 af[4], bf[TN];
#pragma unroll
      for (int t = 0; t < 4; ++t)
        af[t] = *(const short8*)(As + (wm + t * 16 + l15) * 64 + (((ks * 4 + l4) ^ sw)) * 8);
#pragma unroll
      for (int t = 0; t < TN; ++t)
        bf[t] = *(const short8*)(Bs + (wn + t * 16 + l15) * 64 + (((ks * 4 + l4) ^ sw)) * 8);
#pragma unroll
      for (int tm = 0; tm < 4; ++tm)
#pragma unroll
        for (int tn = 0; tn < TN; ++tn)
          acc[tm][tn] = TRANS ? MFMA16(bf[tn], af[tm], acc[tm][tn])
                              : MFMA16(af[tm], bf[tn], acc[tm][tn]);
    }
  }

  if (TRANS) {
    // acc holds transposed fragments: lane l15 -> row (A index), l4*4+r -> col (B index)
#pragma unroll
    for (int tn = 0; tn < TN; ++tn) {
      int colb = bn * BN + wn + tn * 16 + l4 * 4;
      float4 bv4 = *(const float4*)(bias + colb);
#pragma unroll
      for (int tm = 0; tm < 4; ++tm) {
        int row = bm * 128 + wm + tm * 16 + l15;
        float4 v;
        v.x = acc[tm][tn][0] + bv4.x;
        v.y = acc[tm][tn][1] + bv4.y;
        v.z = acc[tm][tn][2] + bv4.z;
        v.w = acc[tm][tn][3] + bv4.w;
        *(float4*)((float*)C + (size_t)row * N + colb) = v;
      }
    }
    return;
  }

#pragma unroll
  for (int tn = 0; tn < TN; ++tn) {
    int col = bn * BN + wn + tn * 16 + l15;
    float bv = bias[col];
    float sc = (col < scaleNend) ? scaleVal : 1.0f;
    if (!SPLITV || col < 2048) {
#pragma unroll
      for (int tm = 0; tm < 4; ++tm) {
        int row0 = bm * 128 + wm + tm * 16 + l4 * 4;
#pragma unroll
        for (int r = 0; r < 4; ++r) {
          float v = (acc[tm][tn][r] + bv) * sc;
          store_out(C + (size_t)(row0 + r) * N + col, v);
        }
      }
    } else {
      int hv = (col - 2048) >> 6, d = (col - 2048) & 63;
#pragma unroll
      for (int tm = 0; tm < 4; ++tm) {
        int row0 = bm * 128 + wm + tm * 16 + l4 * 4;
        int bb = row0 >> 11, s0 = row0 & 2047;
        union { unsigned long long ll; u16 s[4]; } o;
#pragma unroll
        for (int r = 0; r < 4; ++r) o.s[r] = f2bf(acc[tm][tn][r] + bv);
        // rows row0..row0+3 are consecutive (s&7) slots of one octet -> one 8B store
        size_t idx = ((((size_t)(bb * 16 + hv) * 128 + (s0 >> 4)) * 2 + ((s0 >> 3) & 1)) * 64 + d) * 8 +
                     (s0 & 7);
        *(unsigned long long*)(Vtc + idx) = o.ll;
      }
    }
  }
}

// ---------------- attention v5: r0 tiling @ (256,3) + ONE-SUPERSTEP S^T/PV SKEW ----------------
// OCCUPANCY VERDICT (r1/r3/r4): the 64q x 512k wave tile needs ~148-160 regs (Oacc 64 +
// qf 32 + kf 16 + vf 16 + temps); every attempt to force 4 blocks/CU (128 regs) spilled
// Oacc to scratch (216-340 MB write traffic). 12 waves/CU is the ceiling for this tiling.
// TILING LESSON (r2): shrinking the wave tile to fit 128 regs halves K/V reuse; 1.8x worse.
// THIS ROUND: cut T_block instead. r0's superstep is fully serial per wave:
//   load -> S^T MFMA -> exp2 -> pack -> P store(LDS) -> P read(LDS) -> PV MFMA
// (MfmaUtil 18.7 + VALUBusy 28.8 at r0 => ~90% of each wave's time is dependency stall.)
// Skew by one superstep: iter c computes S^T(c) into P-buf[c&1] while PV(c-1) consumes
// P-buf[(c-1)&1]. The LDS round-trip gets a full iteration of slack; S^T(c) and PV(c-1)
// MFMAs are independent (back-to-back matrix issue); exp2(c) overlaps PV(c-1).
// vf(c-1) is RE-LOADED at iter c (L2-resident) so no carried register: footprint stays
// ~148 = r0's. #pragma unroll 1 pins the shape (r3 lesson: unroll batching re-inflates
// the live set). LDS: per-wave 5120 u16 (P dbuf 2x2560; O-combine overlays post-loop)
// = 40960 B/block, x3 = 123 KB <= 160 KB.
// GATE: FETCH ~12.6 MB / WRITE ~8 MB (no spill). If WRITE balloons -> revert to exact r0.
__global__ __launch_bounds__(256, 3) void attn_kernel(const u16* __restrict__ QKV,
                                                      const u16* __restrict__ Vtc,
                                                      u16* __restrict__ Ob) {
  // per-wave region: 5120 u16 = P double-buffer [2][64 q][stride 40] (2x2560),
  // overlaid post-loop by Osum bf16 [64][stride 72] (4608) + l f32[64] at 4608.
  __shared__ __attribute__((aligned(16))) u16 lds[4 * 5120];  // 40960 B
  const int tid = threadIdx.x;
  const int w = tid >> 6, lane = tid & 63;
  const int l15 = lane & 15, l4 = lane >> 4;
  const int lin = blockIdx.x;                 // 1024 blocks
  const int xcd = lin & 7, sblk = lin >> 3;   // sblk in [0,128)
  const int bh = xcd * 4 + (sblk & 3);        // 4 bh per XCD
  const int q0 = (sblk >> 2) * 64;            // 32 q-tiles of 64
  const int b = bh >> 4, h = bh & 15;

  u16* const Pw = lds + w * 5120;

  // Q fragments (B-operand of S^T): rows q0 + tq*16 + l15, k(d) = s*32 + l4*8
  short8 qf[4][2];
  {
    const u16* Qb = QKV + (size_t)(b * 2048 + q0) * 3072 + h * 64;
#pragma unroll
    for (int tq = 0; tq < 4; ++tq)
#pragma unroll
      for (int s = 0; s < 2; ++s)
        qf[tq][s] = *(const short8*)(Qb + (size_t)(tq * 16 + l15) * 3072 + s * 32 + l4 * 8);
  }

  floatx4 Oacc[4][4];
#pragma unroll
  for (int i = 0; i < 4; ++i)
#pragma unroll
    for (int j = 0; j < 4; ++j) Oacc[i][j] = (floatx4){0.f, 0.f, 0.f, 0.f};
  float lpart[4] = {0.f, 0.f, 0.f, 0.f};

  const u16* const Kb = QKV + (size_t)(b * 2048) * 3072 + 1024 + h * 64;  // + key*3072
  const u16* const Vw = Vtc + (size_t)bh * 131072 + (size_t)w * 32768;    // wave's 512 keys
  const int kw0 = w * 512;

  // ---- S^T for one 32-key superstep c into P buffer pb ----
  auto do_st = [&](int c, u16* pb) {
    const int key0 = kw0 + c * 32;
    short8 kf[2][2];
#pragma unroll
    for (int t = 0; t < 2; ++t)
#pragma unroll
      for (int s = 0; s < 2; ++s)
        kf[t][s] = *(const short8*)(Kb + (size_t)(key0 + t * 16 + l15) * 3072 + s * 32 + l4 * 8);
#pragma unroll
    for (int t = 0; t < 2; ++t)
#pragma unroll
      for (int tq = 0; tq < 4; ++tq) {
        floatx4 s = (floatx4){0.f, 0.f, 0.f, 0.f};
        s = MFMA16(kf[t][0], qf[tq][0], s);
        s = MFMA16(kf[t][1], qf[tq][1], s);
        float p0 = fexp2(s[0]), p1 = fexp2(s[1]), p2 = fexp2(s[2]), p3 = fexp2(s[3]);
        lpart[tq] += (p0 + p1) + (p2 + p3);
        unsigned lo = pk2(p1, p0), hi = pk2(p3, p2);
        *(unsigned long long*)(pb + (size_t)(tq * 16 + l15) * 40 + t * 16 + l4 * 4) =
            ((unsigned long long)hi << 32) | lo;
      }
  };

  // ---- PV for superstep c from P buffer pb (vf re-loaded from L2, no carried reg) ----
  auto do_pv = [&](int c, const u16* pb) {
    short8 vf[4];
#pragma unroll
    for (int td = 0; td < 4; ++td)
      vf[td] = *(const short8*)(Vw + (size_t)c * 2048 + l4 * 512 + (td * 16 + l15) * 8);
    short8 pf[4];
#pragma unroll
    for (int tq = 0; tq < 4; ++tq)
      pf[tq] = *(const short8*)(pb + (size_t)(tq * 16 + l15) * 40 + l4 * 8);
#pragma unroll
    for (int td = 0; td < 4; ++td)
#pragma unroll
      for (int tq = 0; tq < 4; ++tq) Oacc[tq][td] = MFMA16(pf[tq], vf[td], Oacc[tq][td]);
  };

  // prologue: fill P buffer 0
  do_st(0, Pw);
  // steady state: S^T(c) -> buf[c&1] while PV(c-1) drains buf[(c-1)&1]
#pragma unroll 1
  for (int c = 1; c < 16; ++c) {
    do_st(c, Pw + (c & 1) * 2560);
    do_pv(c - 1, Pw + ((c - 1) & 1) * 2560);
  }
  // epilogue
  do_pv(15, Pw + 2560);

  // per-wave l reduction across l4 key-groups (full 512-key sums per q)
  float lr[4];
#pragma unroll
  for (int tq = 0; tq < 4; ++tq) {
    float l = lpart[tq];
    l += __shfl_xor(l, 16);
    l += __shfl_xor(l, 32);
    lr[tq] = l;
  }

  // write per-wave partials (own region; own P reads already retired in-order)
#pragma unroll
  for (int tq = 0; tq < 4; ++tq)
#pragma unroll
    for (int td = 0; td < 4; ++td)
#pragma unroll
      for (int r = 0; r < 4; ++r)
        Pw[(size_t)(tq * 16 + l4 * 4 + r) * 72 + td * 16 + l15] = f2bf(Oacc[tq][td][r]);
  if (l4 == 0) {
    float* Lw = (float*)(Pw + 4608);
#pragma unroll
    for (int tq = 0; tq < 4; ++tq) Lw[tq * 16 + l15] = lr[tq];
  }
  __syncthreads();

  // combine: thread -> (row = tid>>2 of 64, 16 cols); sum 4 wave partials
  {
    int row = tid >> 2, c0 = (tid & 3) * 16;
    float acc[16];
#pragma unroll
    for (int j = 0; j < 16; ++j) acc[j] = 0.f;
    float lsum = 0.f;
#pragma unroll
    for (int wv = 0; wv < 4; ++wv) {
      const u16* R = lds + wv * 5120;
      lsum += ((const float*)(R + 4608))[row];
      U128u x1, x2;
      x1.q = *(const uint4*)(R + (size_t)row * 72 + c0);
      x2.q = *(const uint4*)(R + (size_t)row * 72 + c0 + 8);
#pragma unroll
      for (int j = 0; j < 8; ++j) { acc[j] += bf2f(x1.s[j]); acc[8 + j] += bf2f(x2.s[j]); }
    }
    float inv = 1.0f / lsum;
    U128u o1, o2;
#pragma unroll
    for (int j = 0; j < 8; ++j) { o1.s[j] = f2bf(acc[j] * inv); o2.s[j] = f2bf(acc[8 + j] * inv); }
    u16* Op = Ob + (size_t)(b * 2048 + q0 + row) * 1024 + h * 64 + c0;
    *(uint4*)Op = o1.q;
    *(uint4*)(Op + 8) = o2.q;
  }
}

// ---------------- launch ----------------

extern "C" void kernel_launch(void* const* d_in, const int* in_sizes, int n_in,
                              void* d_out, int out_size, void* d_ws, size_t ws_size,
                              hipStream_t stream) {
  const float* x  = (const float*)d_in[0];
  const float* Wq = (const float*)d_in[1];
  const float* bq = (const float*)d_in[2];
  const float* Wk = (const float*)d_in[3];
  const float* bk = (const float*)d_in[4];
  const float* Wv = (const float*)d_in[5];
  const float* bv = (const float*)d_in[6];
  const float* Wo = (const float*)d_in[7];
  const float* bo = (const float*)d_in[8];

  char* p = (char*)d_ws;
  u16* Xb   = (u16*)p; p += (size_t)4096 * 1024 * 2;   // x bf16
  u16* Wt   = (u16*)p; p += (size_t)3072 * 1024 * 2;   // W_all^T bf16 [n][d]
  u16* QKV  = (u16*)p; p += (size_t)4096 * 3072 * 2;   // [token][3072] bf16; Q pre-scaled, V third unused
  u16* Vtc  = (u16*)p; p += (size_t)32 * 128 * 2 * 64 * 8 * 2;  // V chunked: [bh][v][o][d][k8]
  u16* Ob   = (u16*)p; p += (size_t)4096 * 1024 * 2;   // attention out bf16 (normalized)
  u16* Wob  = (u16*)p; p += (size_t)1024 * 1024 * 2;   // Wo bf16 [e][d]
  float* ball = (float*)p; p += 3072 * sizeof(float);

  const float qscale = 0.125f * 1.4426950408889634f;  // (1/sqrt(64)) * log2(e)

  prep_all<<<8192, 256, 0, stream>>>(x, Wo, Wq, bq, Wk, bk, Wv, bv, Xb, Wob, Wt, ball);
  // QKV: BN=96 -> 32x32 = 1024 blocks = 4 blocks/CU (occupancy; was 768 = 3/CU)
  gemm_bt<96, true, false, u16><<<1024, 256, 0, stream>>>(Xb, Wt, ball, QKV, Vtc,
                                                          4096, 3072, 1024, 1024, qscale);
  attn_kernel<<<1024, 256, 0, stream>>>(QKV, Vtc, Ob);
  // out-proj: TRANS epilogue -> float4 stores
  gemm_bt<64, false, true, float><<<512, 256, 0, stream>>>(Ob, Wob, bo, (float*)d_out, nullptr,
                                                           4096, 1024, 1024, 0, 1.0f);
}

// Round 6
// 192.154 us; speedup vs baseline: 1.5370x; 1.0422x over previous
//
#include <hip/hip_runtime.h>
#include <hip/hip_bf16.h>

typedef unsigned short u16;
typedef short short8 __attribute__((ext_vector_type(8)));
typedef float floatx4 __attribute__((ext_vector_type(4)));

#define MFMA16(a, b, c) __builtin_amdgcn_mfma_f32_16x16x32_bf16((a), (b), (c), 0, 0, 0)

union U128u { uint4 q; u16 s[8]; };

__device__ __forceinline__ u16 f2bf(float f) {
  union { float f; unsigned u; } v; v.f = f;
  unsigned r = v.u + 0x7fffu + ((v.u >> 16) & 1u);
  return (u16)(r >> 16);
}

__device__ __forceinline__ float bf2f(u16 s) {
  union { unsigned u; float f; } v; v.u = ((unsigned)s) << 16;
  return v.f;
}

// pack two f32 -> bf16x2 (round-half-up) with one v_perm (attn P only)
__device__ __forceinline__ unsigned pk2(float hi, float lo) {
  union { float f; unsigned u; } a, b;
  a.f = hi; b.f = lo;
  return __builtin_amdgcn_perm(a.u + 0x8000u, b.u + 0x8000u, 0x07060302u);
}

__device__ __forceinline__ float fexp2(float x) {
#if __has_builtin(__builtin_amdgcn_exp2f)
  return __builtin_amdgcn_exp2f(x);
#else
  return exp2f(x);
#endif
}

// async global->LDS, 16B per lane. lds pointer must be wave-uniform. (GEMMs only.)
__device__ __forceinline__ void async16(const u16* g, u16* l) {
  __builtin_amdgcn_global_load_lds(
      (const __attribute__((address_space(1))) unsigned int*)g,
      (__attribute__((address_space(3))) unsigned int*)l, 16, 0, 0);
}

// ---------------- merged prep: cast x, cast Wo, repack Wqkv + biases ----------------

__global__ __launch_bounds__(256) void prep_all(
    const float* __restrict__ x, const float* __restrict__ Wo,
    const float* __restrict__ Wq, const float* __restrict__ bq,
    const float* __restrict__ Wk, const float* __restrict__ bk,
    const float* __restrict__ Wv, const float* __restrict__ bv,
    u16* __restrict__ Xb, u16* __restrict__ Wob,
    u16* __restrict__ Wt, float* __restrict__ ball) {
  int bid = blockIdx.x;
  int tid = threadIdx.x;
  if (bid < 5120) {
    // cast: blocks [0,4096) -> x (1048576 float4), [4096,5120) -> Wo (262144 float4)
    const float* src = bid < 4096 ? x : Wo;
    u16* dst = bid < 4096 ? Xb : Wob;
    int i = (bid < 4096 ? bid : bid - 4096) * 256 + tid;
    float4 v = ((const float4*)src)[i];
    union { unsigned long long ll; u16 s[4]; } o;
    o.s[0] = f2bf(v.x); o.s[1] = f2bf(v.y); o.s[2] = f2bf(v.z); o.s[3] = f2bf(v.w);
    ((unsigned long long*)dst)[i] = o.ll;
    return;
  }
  int id = (bid - 5120) * 256 + tid;  // 786432 total
  int kk4 = id & 15;
  int d = (id >> 4) & 1023;
  int h = (id >> 14) & 15;
  int wsel = id >> 18;
  const float* W = wsel == 0 ? Wq : (wsel == 1 ? Wk : Wv);
  float4 v = *(const float4*)(W + ((size_t)(h * 1024 + d)) * 64 + kk4 * 4);
  int nb = wsel * 1024 + h * 64 + kk4 * 4;
  Wt[(size_t)(nb + 0) * 1024 + d] = f2bf(v.x);
  Wt[(size_t)(nb + 1) * 1024 + d] = f2bf(v.y);
  Wt[(size_t)(nb + 2) * 1024 + d] = f2bf(v.z);
  Wt[(size_t)(nb + 3) * 1024 + d] = f2bf(v.w);
  if (id < 3072) {
    int ws2 = id >> 10, hk = id & 1023;
    const float* bsrc = ws2 == 0 ? bq : (ws2 == 1 ? bk : bv);
    ball[id] = bsrc[hk];
  }
}

// ---------------- GEMM: C[M,N] = A[M,K] * B^T (B stored [N,K]) + bias, opt scale --------------
// (QKV projection only now; out-proj moved to gemm_out64 for 4 blocks/CU.)

__device__ __forceinline__ void store_out(u16* p, float v) { *p = f2bf(v); }
__device__ __forceinline__ void store_out(float* p, float v) { *p = v; }

template <int BN, bool SPLITV, bool TRANS, typename OutT>
__global__ __launch_bounds__(256, 4) void gemm_bt(
    const u16* __restrict__ A, const u16* __restrict__ B,
    const float* __restrict__ bias, OutT* __restrict__ C,
    u16* __restrict__ Vtc,
    int M, int N, int K, int scaleNend, float scaleVal) {
  constexpr int TN = BN / 32;  // n-tiles per wave
  __shared__ __attribute__((aligned(16))) u16 As[128 * 64];
  __shared__ __attribute__((aligned(16))) u16 Bs[BN * 64];
  const int tid = threadIdx.x;
  const int w = tid >> 6, lane = tid & 63;
  const int l15 = lane & 15, l4 = lane >> 4;
  const int lin = blockIdx.x;
  const int xcd = lin & 7, sblk = lin >> 3;
  const int bm = xcd * 4 + (sblk & 3);   // M=4096 -> 32 bm tiles, 4 per XCD
  const int bn = sblk >> 2;
  const int wm = (w & 1) * 64, wn = (w >> 1) * (BN / 2);

  floatx4 acc[4][TN];
#pragma unroll
  for (int i = 0; i < 4; ++i)
#pragma unroll
    for (int j = 0; j < TN; ++j) acc[i][j] = (floatx4){0.f, 0.f, 0.f, 0.f};

  for (int k0 = 0; k0 < K; k0 += 64) {
    __syncthreads();
#pragma unroll
    for (int j = 0; j < 4; ++j) {  // A: 128 rows x 8 chunks = 1024 slots
      int i = j * 256 + tid;
      int row = i >> 3, c = (i & 7) ^ (row & 7);
      async16(A + (size_t)(bm * 128 + row) * K + k0 + c * 8, As + (j * 256 + w * 64) * 8);
    }
#pragma unroll
    for (int j = 0; j < BN / 32; ++j) {  // B: BN rows x 8 chunks
      int i = j * 256 + tid;
      int row = i >> 3, c = (i & 7) ^ (row & 7);
      async16(B + (size_t)(bn * BN + row) * K + k0 + c * 8, Bs + (j * 256 + w * 64) * 8);
    }
    __syncthreads();
    const int sw = l15 & 7;
#pragma unroll
    for (int ks = 0; ks < 2; ++ks) {
      short8 af[4], bf[TN];
#pragma unroll
      for (int t = 0; t < 4; ++t)
        af[t] = *(const short8*)(As + (wm + t * 16 + l15) * 64 + (((ks * 4 + l4) ^ sw)) * 8);
#pragma unroll
      for (int t = 0; t < TN; ++t)
        bf[t] = *(const short8*)(Bs + (wn + t * 16 + l15) * 64 + (((ks * 4 + l4) ^ sw)) * 8);
#pragma unroll
      for (int tm = 0; tm < 4; ++tm)
#pragma unroll
        for (int tn = 0; tn < TN; ++tn)
          acc[tm][tn] = TRANS ? MFMA16(bf[tn], af[tm], acc[tm][tn])
                              : MFMA16(af[tm], bf[tn], acc[tm][tn]);
    }
  }

  if (TRANS) {
    // acc holds transposed fragments: lane l15 -> row (A index), l4*4+r -> col (B index)
#pragma unroll
    for (int tn = 0; tn < TN; ++tn) {
      int colb = bn * BN + wn + tn * 16 + l4 * 4;
      float4 bv4 = *(const float4*)(bias + colb);
#pragma unroll
      for (int tm = 0; tm < 4; ++tm) {
        int row = bm * 128 + wm + tm * 16 + l15;
        float4 v;
        v.x = acc[tm][tn][0] + bv4.x;
        v.y = acc[tm][tn][1] + bv4.y;
        v.z = acc[tm][tn][2] + bv4.z;
        v.w = acc[tm][tn][3] + bv4.w;
        *(float4*)((float*)C + (size_t)row * N + colb) = v;
      }
    }
    return;
  }

#pragma unroll
  for (int tn = 0; tn < TN; ++tn) {
    int col = bn * BN + wn + tn * 16 + l15;
    float bv = bias[col];
    float sc = (col < scaleNend) ? scaleVal : 1.0f;
    if (!SPLITV || col < 2048) {
#pragma unroll
      for (int tm = 0; tm < 4; ++tm) {
        int row0 = bm * 128 + wm + tm * 16 + l4 * 4;
#pragma unroll
        for (int r = 0; r < 4; ++r) {
          float v = (acc[tm][tn][r] + bv) * sc;
          store_out(C + (size_t)(row0 + r) * N + col, v);
        }
      }
    } else {
      int hv = (col - 2048) >> 6, d = (col - 2048) & 63;
#pragma unroll
      for (int tm = 0; tm < 4; ++tm) {
        int row0 = bm * 128 + wm + tm * 16 + l4 * 4;
        int bb = row0 >> 11, s0 = row0 & 2047;
        union { unsigned long long ll; u16 s[4]; } o;
#pragma unroll
        for (int r = 0; r < 4; ++r) o.s[r] = f2bf(acc[tm][tn][r] + bv);
        // rows row0..row0+3 are consecutive (s&7) slots of one octet -> one 8B store
        size_t idx = ((((size_t)(bb * 16 + hv) * 128 + (s0 >> 4)) * 2 + ((s0 >> 3) & 1)) * 64 + d) * 8 +
                     (s0 & 7);
        *(unsigned long long*)(Vtc + idx) = o.ll;
      }
    }
  }
}

// ---------------- out-proj GEMM: BM=64, BN=64 -> 1024 blocks = 4 blocks/CU ----------------
// r5 analysis: gemm_bt<64> ran 512 blocks = 2 blocks/CU (half-empty machine, same disease
// as r0's attn tail). BM 128->64 doubles the grid: 64 bm x 16 bn = 1024 = 4/CU.
// LDS 16 KB/block (x4 = 64 KB), acc[2][2]+frags ~60 regs -> (256,4) genuinely fits.
// Per XCD: 8 consecutive bm A-panels (1 MB) + Wob (2 MB) L2-resident.
// TRANS operand order -> float4 epilogue stores (16B/lane).
__global__ __launch_bounds__(256, 4) void gemm_out64(
    const u16* __restrict__ A, const u16* __restrict__ B,
    const float* __restrict__ bias, float* __restrict__ C) {
  __shared__ __attribute__((aligned(16))) u16 As[64 * 64];
  __shared__ __attribute__((aligned(16))) u16 Bs[64 * 64];
  const int tid = threadIdx.x;
  const int w = tid >> 6, lane = tid & 63;
  const int l15 = lane & 15, l4 = lane >> 4;
  const int lin = blockIdx.x;                // 1024 blocks
  const int xcd = lin & 7, sblk = lin >> 3;  // sblk in [0,128)
  const int bm = xcd * 8 + (sblk & 7);       // 64 bm tiles, 8 per XCD
  const int bn = sblk >> 3;                  // 16 bn tiles
  const int wm = (w & 1) * 32, wn = (w >> 1) * 32;

  floatx4 acc[2][2];
#pragma unroll
  for (int i = 0; i < 2; ++i)
#pragma unroll
    for (int j = 0; j < 2; ++j) acc[i][j] = (floatx4){0.f, 0.f, 0.f, 0.f};

  for (int k0 = 0; k0 < 1024; k0 += 64) {
    __syncthreads();
#pragma unroll
    for (int j = 0; j < 2; ++j) {  // A: 64 rows x 8 chunks = 512 slots
      int i = j * 256 + tid;
      int row = i >> 3, c = (i & 7) ^ (row & 7);
      async16(A + (size_t)(bm * 64 + row) * 1024 + k0 + c * 8, As + (j * 256 + w * 64) * 8);
    }
#pragma unroll
    for (int j = 0; j < 2; ++j) {  // B: 64 rows x 8 chunks
      int i = j * 256 + tid;
      int row = i >> 3, c = (i & 7) ^ (row & 7);
      async16(B + (size_t)(bn * 64 + row) * 1024 + k0 + c * 8, Bs + (j * 256 + w * 64) * 8);
    }
    __syncthreads();
    const int sw = l15 & 7;
#pragma unroll
    for (int ks = 0; ks < 2; ++ks) {
      short8 af[2], bf[2];
#pragma unroll
      for (int t = 0; t < 2; ++t)
        af[t] = *(const short8*)(As + (wm + t * 16 + l15) * 64 + (((ks * 4 + l4) ^ sw)) * 8);
#pragma unroll
      for (int t = 0; t < 2; ++t)
        bf[t] = *(const short8*)(Bs + (wn + t * 16 + l15) * 64 + (((ks * 4 + l4) ^ sw)) * 8);
#pragma unroll
      for (int tm = 0; tm < 2; ++tm)
#pragma unroll
        for (int tn = 0; tn < 2; ++tn)
          acc[tm][tn] = MFMA16(bf[tn], af[tm], acc[tm][tn]);  // TRANS order
    }
  }

  // TRANS epilogue: lane l15 -> C row, l4*4+r -> C col; float4 stores
#pragma unroll
  for (int tn = 0; tn < 2; ++tn) {
    int colb = bn * 64 + wn + tn * 16 + l4 * 4;
    float4 bv4 = *(const float4*)(bias + colb);
#pragma unroll
    for (int tm = 0; tm < 2; ++tm) {
      int row = bm * 64 + wm + tm * 16 + l15;
      float4 v;
      v.x = acc[tm][tn][0] + bv4.x;
      v.y = acc[tm][tn][1] + bv4.y;
      v.z = acc[tm][tn][2] + bv4.z;
      v.w = acc[tm][tn][3] + bv4.w;
      *(float4*)(C + (size_t)row * 1024 + colb) = v;
    }
  }
}

// ---------------- attention v6: skewed S^T/PV + one-superstep kf REGISTER PREFETCH ------------
// OCCUPANCY VERDICT (r1/r3/r4): 64q x 512k wave tile needs ~148-160 regs; forcing 128
// (4 blocks/CU) always spills Oacc. 12 waves/CU is the ceiling. TILING LESSON (r2):
// smaller wave tiles halve K/V reuse; 1.8x worse. SKEW (r5, kept): S^T(c) -> P-buf[c&1]
// while PV(c-1) drains buf[(c-1)&1]; +6 us.
// THIS ROUND: r5 counters (MfmaUtil 21, VALUBusy 32, occ 21) = still ~47% stalled. The
// remaining serial stall: kf loads at top of do_st(c) are used IMMEDIATELY (~200 cyc L2
// latency exposed x16 supersteps; compiler won't hoist loads across the back-edge).
// Fix: load kf(c+1) into a second reg set at the top of body c; do_st(c) starts with
// zero wait; kf(c+1) latency is covered by the whole body (S^T + exp2 + PV ~600 cyc).
// Cost: +16 VGPR -> ~160 combined <= 168 (3-wave quantum). Explicit copy, #pragma
// unroll 1 pinned (r9: no lambda rotation). GATE: WRITE ~8.2 MB; if ballooned -> revert.
__global__ __launch_bounds__(256, 3) void attn_kernel(const u16* __restrict__ QKV,
                                                      const u16* __restrict__ Vtc,
                                                      u16* __restrict__ Ob) {
  // per-wave region: 5120 u16 = P double-buffer [2][64 q][stride 40] (2x2560),
  // overlaid post-loop by Osum bf16 [64][stride 72] (4608) + l f32[64] at 4608.
  __shared__ __attribute__((aligned(16))) u16 lds[4 * 5120];  // 40960 B
  const int tid = threadIdx.x;
  const int w = tid >> 6, lane = tid & 63;
  const int l15 = lane & 15, l4 = lane >> 4;
  const int lin = blockIdx.x;                 // 1024 blocks
  const int xcd = lin & 7, sblk = lin >> 3;   // sblk in [0,128)
  const int bh = xcd * 4 + (sblk & 3);        // 4 bh per XCD
  const int q0 = (sblk >> 2) * 64;            // 32 q-tiles of 64
  const int b = bh >> 4, h = bh & 15;

  u16* const Pw = lds + w * 5120;

  // Q fragments (B-operand of S^T): rows q0 + tq*16 + l15, k(d) = s*32 + l4*8
  short8 qf[4][2];
  {
    const u16* Qb = QKV + (size_t)(b * 2048 + q0) * 3072 + h * 64;
#pragma unroll
    for (int tq = 0; tq < 4; ++tq)
#pragma unroll
      for (int s = 0; s < 2; ++s)
        qf[tq][s] = *(const short8*)(Qb + (size_t)(tq * 16 + l15) * 3072 + s * 32 + l4 * 8);
  }

  floatx4 Oacc[4][4];
#pragma unroll
  for (int i = 0; i < 4; ++i)
#pragma unroll
    for (int j = 0; j < 4; ++j) Oacc[i][j] = (floatx4){0.f, 0.f, 0.f, 0.f};
  float lpart[4] = {0.f, 0.f, 0.f, 0.f};

  const u16* const Kb = QKV + (size_t)(b * 2048) * 3072 + 1024 + h * 64;  // + key*3072
  const u16* const Vw = Vtc + (size_t)bh * 131072 + (size_t)w * 32768;    // wave's 512 keys
  const int kw0 = w * 512;

  // ---- issue K fragment loads for superstep c ----
  auto load_kf = [&](int c, short8 kf[2][2]) {
    const int key0 = kw0 + c * 32;
#pragma unroll
    for (int t = 0; t < 2; ++t)
#pragma unroll
      for (int s = 0; s < 2; ++s)
        kf[t][s] = *(const short8*)(Kb + (size_t)(key0 + t * 16 + l15) * 3072 + s * 32 + l4 * 8);
  };

  // ---- S^T for one 32-key superstep into P buffer pb (kf already in regs) ----
  auto do_st = [&](const short8 kf[2][2], u16* pb) {
#pragma unroll
    for (int t = 0; t < 2; ++t)
#pragma unroll
      for (int tq = 0; tq < 4; ++tq) {
        floatx4 s = (floatx4){0.f, 0.f, 0.f, 0.f};
        s = MFMA16(kf[t][0], qf[tq][0], s);
        s = MFMA16(kf[t][1], qf[tq][1], s);
        float p0 = fexp2(s[0]), p1 = fexp2(s[1]), p2 = fexp2(s[2]), p3 = fexp2(s[3]);
        lpart[tq] += (p0 + p1) + (p2 + p3);
        unsigned lo = pk2(p1, p0), hi = pk2(p3, p2);
        *(unsigned long long*)(pb + (size_t)(tq * 16 + l15) * 40 + t * 16 + l4 * 4) =
            ((unsigned long long)hi << 32) | lo;
      }
  };

  // ---- PV for superstep c from P buffer pb (vf re-loaded from L2, no carried reg) ----
  auto do_pv = [&](int c, const u16* pb) {
    short8 vf[4];
#pragma unroll
    for (int td = 0; td < 4; ++td)
      vf[td] = *(const short8*)(Vw + (size_t)c * 2048 + l4 * 512 + (td * 16 + l15) * 8);
    short8 pf[4];
#pragma unroll
    for (int tq = 0; tq < 4; ++tq)
      pf[tq] = *(const short8*)(pb + (size_t)(tq * 16 + l15) * 40 + l4 * 8);
#pragma unroll
    for (int td = 0; td < 4; ++td)
#pragma unroll
      for (int tq = 0; tq < 4; ++tq) Oacc[tq][td] = MFMA16(pf[tq], vf[td], Oacc[tq][td]);
  };

  short8 kfc[2][2];
  load_kf(0, kfc);
  {  // prologue c=0: prefetch kf(1), S^T(0) -> buf0
    short8 kfn[2][2];
    load_kf(1, kfn);
    do_st(kfc, Pw);
#pragma unroll
    for (int t = 0; t < 2; ++t)
#pragma unroll
      for (int s = 0; s < 2; ++s) kfc[t][s] = kfn[t][s];
  }
  // steady state c=1..14: prefetch kf(c+1); S^T(c) with resident kfc; PV(c-1)
#pragma unroll 1
  for (int c = 1; c < 15; ++c) {
    short8 kfn[2][2];
    load_kf(c + 1, kfn);
    do_st(kfc, Pw + (c & 1) * 2560);
    do_pv(c - 1, Pw + ((c - 1) & 1) * 2560);
#pragma unroll
    for (int t = 0; t < 2; ++t)
#pragma unroll
      for (int s = 0; s < 2; ++s) kfc[t][s] = kfn[t][s];
  }
  // epilogue c=15
  do_st(kfc, Pw + 2560);
  do_pv(14, Pw);
  do_pv(15, Pw + 2560);

  // per-wave l reduction across l4 key-groups (full 512-key sums per q)
  float lr[4];
#pragma unroll
  for (int tq = 0; tq < 4; ++tq) {
    float l = lpart[tq];
    l += __shfl_xor(l, 16);
    l += __shfl_xor(l, 32);
    lr[tq] = l;
  }

  // write per-wave partials (own region; own P reads already retired in-order)
#pragma unroll
  for (int tq = 0; tq < 4; ++tq)
#pragma unroll
    for (int td = 0; td < 4; ++td)
#pragma unroll
      for (int r = 0; r < 4; ++r)
        Pw[(size_t)(tq * 16 + l4 * 4 + r) * 72 + td * 16 + l15] = f2bf(Oacc[tq][td][r]);
  if (l4 == 0) {
    float* Lw = (float*)(Pw + 4608);
#pragma unroll
    for (int tq = 0; tq < 4; ++tq) Lw[tq * 16 + l15] = lr[tq];
  }
  __syncthreads();

  // combine: thread -> (row = tid>>2 of 64, 16 cols); sum 4 wave partials
  {
    int row = tid >> 2, c0 = (tid & 3) * 16;
    float acc[16];
#pragma unroll
    for (int j = 0; j < 16; ++j) acc[j] = 0.f;
    float lsum = 0.f;
#pragma unroll
    for (int wv = 0; wv < 4; ++wv) {
      const u16* R = lds + wv * 5120;
      lsum += ((const float*)(R + 4608))[row];
      U128u x1, x2;
      x1.q = *(const uint4*)(R + (size_t)row * 72 + c0);
      x2.q = *(const uint4*)(R + (size_t)row * 72 + c0 + 8);
#pragma unroll
      for (int j = 0; j < 8; ++j) { acc[j] += bf2f(x1.s[j]); acc[8 + j] += bf2f(x2.s[j]); }
    }
    float inv = 1.0f / lsum;
    U128u o1, o2;
#pragma unroll
    for (int j = 0; j < 8; ++j) { o1.s[j] = f2bf(acc[j] * inv); o2.s[j] = f2bf(acc[8 + j] * inv); }
    u16* Op = Ob + (size_t)(b * 2048 + q0 + row) * 1024 + h * 64 + c0;
    *(uint4*)Op = o1.q;
    *(uint4*)(Op + 8) = o2.q;
  }
}

// ---------------- launch ----------------

extern "C" void kernel_launch(void* const* d_in, const int* in_sizes, int n_in,
                              void* d_out, int out_size, void* d_ws, size_t ws_size,
                              hipStream_t stream) {
  const float* x  = (const float*)d_in[0];
  const float* Wq = (const float*)d_in[1];
  const float* bq = (const float*)d_in[2];
  const float* Wk = (const float*)d_in[3];
  const float* bk = (const float*)d_in[4];
  const float* Wv = (const float*)d_in[5];
  const float* bv = (const float*)d_in[6];
  const float* Wo = (const float*)d_in[7];
  const float* bo = (const float*)d_in[8];

  char* p = (char*)d_ws;
  u16* Xb   = (u16*)p; p += (size_t)4096 * 1024 * 2;   // x bf16
  u16* Wt   = (u16*)p; p += (size_t)3072 * 1024 * 2;   // W_all^T bf16 [n][d]
  u16* QKV  = (u16*)p; p += (size_t)4096 * 3072 * 2;   // [token][3072] bf16; Q pre-scaled, V third unused
  u16* Vtc  = (u16*)p; p += (size_t)32 * 128 * 2 * 64 * 8 * 2;  // V chunked: [bh][v][o][d][k8]
  u16* Ob   = (u16*)p; p += (size_t)4096 * 1024 * 2;   // attention out bf16 (normalized)
  u16* Wob  = (u16*)p; p += (size_t)1024 * 1024 * 2;   // Wo bf16 [e][d]
  float* ball = (float*)p; p += 3072 * sizeof(float);

  const float qscale = 0.125f * 1.4426950408889634f;  // (1/sqrt(64)) * log2(e)

  prep_all<<<8192, 256, 0, stream>>>(x, Wo, Wq, bq, Wk, bk, Wv, bv, Xb, Wob, Wt, ball);
  // QKV: BN=96 -> 32x32 = 1024 blocks = 4 blocks/CU
  gemm_bt<96, true, false, u16><<<1024, 256, 0, stream>>>(Xb, Wt, ball, QKV, Vtc,
                                                          4096, 3072, 1024, 1024, qscale);
  attn_kernel<<<1024, 256, 0, stream>>>(QKV, Vtc, Ob);
  // out-proj: BM=64 tiles -> 1024 blocks = 4 blocks/CU (was 512 = 2/CU)
  gemm_out64<<<1024, 256, 0, stream>>>(Ob, Wob, bo, (float*)d_out);
}